// Round 8
// baseline (516.103 us; speedup 1.0000x reference)
//
#include <hip/hip_runtime.h>
#include <hip/hip_bf16.h>

#define N_ROWS 8192
#define DIM    128
#define NCLASS 512
#define MARGIN 0.3f

typedef unsigned short u16;
typedef __attribute__((ext_vector_type(8))) short bf16x8;
typedef __attribute__((ext_vector_type(4))) float f32x4;

__device__ inline void load_lds16(const u16* g, u16* l) {
    __builtin_amdgcn_global_load_lds((const __attribute__((address_space(1))) void*)g,
                                     (__attribute__((address_space(3))) void*)l, 16, 0, 0);
}

// ---------------- fused prep: normalize->fb (blocks 0..2047) || class sums (2048..2559) ----------------
__global__ void k_prep2(const float* __restrict__ feat, const int* __restrict__ lab,
                        u16* __restrict__ fb, float* __restrict__ cs, int* __restrict__ hist,
                        int* __restrict__ pcnt) {
    const int t = threadIdx.x, lane = t & 63, w = t >> 6;
    if (blockIdx.x < 2048) {
        // role A: normalize 4 rows -> bf16 fb
        int row = blockIdx.x * 4 + w;
        float2 v = *reinterpret_cast<const float2*>(feat + row * DIM + lane * 2);
        float ss = v.x * v.x + v.y * v.y;
        #pragma unroll
        for (int off = 32; off; off >>= 1) ss += __shfl_xor(ss, off);
        float r = 1.0f / fmaxf(sqrtf(ss), 1e-12f);
        float x = v.x * r, y = v.y * r;
        __hip_bfloat16 bx = __float2bfloat16(x), by = __float2bfloat16(y);
        u16 ux = *reinterpret_cast<u16*>(&bx), uy = *reinterpret_cast<u16*>(&by);
        ushort2 p; p.x = ux; p.y = uy;
        *reinterpret_cast<ushort2*>(fb + row * DIM + lane * 2) = p;
        return;
    }
    // role B: class sum for c (gathers RAW rows, renormalizes in-register)
    __shared__ int s_cnt;
    __shared__ int s_idx[128];
    __shared__ float2 part[4][64];
    const int c = blockIdx.x - 2048;
    if (blockIdx.x == 2048 && t < 65) pcnt[t] = 0;   // zero completion counters each call
    if (t == 0) s_cnt = 0;
    __syncthreads();
    for (int q = t; q < N_ROWS / 4; q += 256) {
        int4 L = reinterpret_cast<const int4*>(lab)[q];
        if (L.x == c) { int p = atomicAdd(&s_cnt, 1); if (p < 128) s_idx[p] = q * 4 + 0; }
        if (L.y == c) { int p = atomicAdd(&s_cnt, 1); if (p < 128) s_idx[p] = q * 4 + 1; }
        if (L.z == c) { int p = atomicAdd(&s_cnt, 1); if (p < 128) s_idx[p] = q * 4 + 2; }
        if (L.w == c) { int p = atomicAdd(&s_cnt, 1); if (p < 128) s_idx[p] = q * 4 + 3; }
    }
    __syncthreads();
    int cnt = s_cnt < 128 ? s_cnt : 128;
    float sA = 0.f, sB = 0.f;          // lane owns dims 2*lane, 2*lane+1
    for (int p = w; p < cnt; p += 4) { // waves split the class rows
        int r = s_idx[p];
        float2 v = *reinterpret_cast<const float2*>(feat + r * DIM + lane * 2);
        float ss = v.x * v.x + v.y * v.y;
        #pragma unroll
        for (int off = 32; off; off >>= 1) ss += __shfl_xor(ss, off);
        float rr = 1.0f / fmaxf(sqrtf(ss), 1e-12f);
        sA += v.x * rr; sB += v.y * rr;
    }
    part[w][lane] = make_float2(sA, sB);
    __syncthreads();
    if (t < 64) {
        float2 p0 = part[0][t], p1 = part[1][t], p2 = part[2][t], p3 = part[3][t];
        float2 o = make_float2((p0.x + p1.x) + (p2.x + p3.x),
                               (p0.y + p1.y) + (p2.y + p3.y));
        *reinterpret_cast<float2*>(cs + c * DIM + t * 2) = o;
    }
    if (t == 0) hist[c] = s_cnt;
}

// ---------------- main: symmetric fused sim-GEMM + masked neg-max + in-kernel finish ----------------
// Upper-triangle tiles: 2080 blocks, tile (bi<=bj) emits row-path (panel bi) and
// col-path (panel bj) masked maxes. Panel p is touched by exactly 64 blocks; the
// 64th (last-block pattern: threadfence + atomicAdd) computes panel p's loss
// partial (pos-dot vs cs + 64-slot neg-max) and the last panel sums 64 partials
// in fixed order -> out. Deterministic: every nbp/lpart slot written exactly once,
// final sums in fixed order.
__global__ __launch_bounds__(512, 4) void k_main(const u16* __restrict__ fb,
                                                 const int* __restrict__ lab,
                                                 float* __restrict__ nbp,
                                                 const float* __restrict__ cs,
                                                 const int* __restrict__ hist,
                                                 int* __restrict__ pcnt,
                                                 float* __restrict__ lpart,
                                                 float* __restrict__ out) {
    __shared__ u16 Bt[128 * 128];         // 32 KB
    __shared__ float redr[2][128];
    __shared__ float redc[4][128];
    __shared__ int s_fin[2];
    __shared__ float sm[8];
    const int t = threadIdx.x;
    const int lane = t & 63, w = t >> 6;
    const int wr = w >> 1, wc = w & 1;
    const int l15 = lane & 15, l4 = lane >> 4;

    // invert linear block id -> (bi, bj) upper triangle, bi<=bj, 64x64 panels
    int tt = blockIdx.x;
    int bi = (int)((129.0f - sqrtf(16641.0f - 8.0f * (float)tt)) * 0.5f);
    while (bi * 64 - bi * (bi - 1) / 2 > tt) --bi;
    while ((bi + 1) * 64 - (bi + 1) * bi / 2 <= tt) ++bi;
    const int bj = bi + (tt - (bi * 64 - bi * (bi - 1) / 2));
    const int i0 = bi * 128, j0 = bj * 128;

    // stage B tile = fb rows j0..j0+127 (2048 x 16B chunks, 4 per thread)
    #pragma unroll
    for (int it = 0; it < 4; ++it) {
        int q = it * 512 + t;
        int brow = q >> 4, kb = q & 15;
        load_lds16(fb + (j0 + brow) * DIM + ((kb ^ (brow & 7)) * 8), Bt + q * 8);
    }

    // A fragments: row = i0 + wr*32 + m*16 + l15, k = ks*32 + l4*8
    bf16x8 a[2][4];
    #pragma unroll
    for (int m = 0; m < 2; ++m)
        #pragma unroll
        for (int ks = 0; ks < 4; ++ks)
            a[m][ks] = *reinterpret_cast<const bf16x8*>(
                fb + (i0 + wr * 32 + m * 16 + l15) * DIM + ks * 32 + l4 * 8);

    int labr[2][4];
    #pragma unroll
    for (int m = 0; m < 2; ++m)
        #pragma unroll
        for (int rg = 0; rg < 4; ++rg)
            labr[m][rg] = lab[i0 + wr * 32 + m * 16 + l4 * 4 + rg];

    int labc[4];
    #pragma unroll
    for (int n = 0; n < 4; ++n) labc[n] = lab[j0 + wc * 64 + n * 16 + l15];

    __syncthreads();   // vmcnt drained -> Bt ready

    f32x4 acc[2][4];
    #pragma unroll
    for (int m = 0; m < 2; ++m)
        #pragma unroll
        for (int n = 0; n < 4; ++n) acc[m][n] = f32x4{0.f, 0.f, 0.f, 0.f};

    __builtin_amdgcn_s_setprio(1);
    #pragma unroll
    for (int ks = 0; ks < 4; ++ks) {
        bf16x8 b[4];
        #pragma unroll
        for (int n = 0; n < 4; ++n) {
            int brow = wc * 64 + n * 16 + l15;
            int kb = ks * 4 + l4;
            b[n] = *reinterpret_cast<const bf16x8*>(
                Bt + brow * DIM + ((kb ^ (brow & 7)) * 8));
        }
        #pragma unroll
        for (int m = 0; m < 2; ++m)
            #pragma unroll
            for (int n = 0; n < 4; ++n)
                acc[m][n] = __builtin_amdgcn_mfma_f32_16x16x32_bf16(a[m][ks], b[n],
                                                                    acc[m][n], 0, 0, 0);
    }
    __builtin_amdgcn_s_setprio(0);

    // masked epilogue: v computed once, feeds row-max AND col-max
    float negp[2][4];
    float colv[4];
    #pragma unroll
    for (int m = 0; m < 2; ++m)
        #pragma unroll
        for (int rg = 0; rg < 4; ++rg) negp[m][rg] = -1e9f;
    #pragma unroll
    for (int n = 0; n < 4; ++n) colv[n] = -1e9f;

    #pragma unroll
    for (int m = 0; m < 2; ++m)
        #pragma unroll
        for (int n = 0; n < 4; ++n) {
            int lc = labc[n];
            #pragma unroll
            for (int rg = 0; rg < 4; ++rg) {
                float s = acc[m][n][rg];
                float v = (labr[m][rg] != lc) ? s : -1e9f;
                negp[m][rg] = fmaxf(negp[m][rg], v);
                colv[n] = fmaxf(colv[n], v);
            }
        }

    // row reduce (16 lanes sharing each row)
    #pragma unroll
    for (int m = 0; m < 2; ++m)
        #pragma unroll
        for (int rg = 0; rg < 4; ++rg) {
            float v = negp[m][rg];
            v = fmaxf(v, __shfl_xor(v, 1));
            v = fmaxf(v, __shfl_xor(v, 2));
            v = fmaxf(v, __shfl_xor(v, 4));
            v = fmaxf(v, __shfl_xor(v, 8));
            negp[m][rg] = v;
        }
    if (l15 == 0) {
        #pragma unroll
        for (int m = 0; m < 2; ++m)
            #pragma unroll
            for (int rg = 0; rg < 4; ++rg)
                redr[wc][wr * 32 + m * 16 + l4 * 4 + rg] = negp[m][rg];
    }

    // col reduce (4 l4 groups sharing each col)
    #pragma unroll
    for (int n = 0; n < 4; ++n) {
        float v = colv[n];
        v = fmaxf(v, __shfl_xor(v, 16));
        v = fmaxf(v, __shfl_xor(v, 32));
        colv[n] = v;
    }
    if (l4 == 0) {
        #pragma unroll
        for (int n = 0; n < 4; ++n)
            redc[wr][wc * 64 + n * 16 + l15] = colv[n];
    }
    __syncthreads();

    if (t < 128) {
        float rv = fmaxf(redr[0][t], redr[1][t]);
        nbp[(i0 + t) * 64 + bj] = rv;                      // row-path slot
        if (bi != bj) {
            float cv = fmaxf(fmaxf(redc[0][t], redc[1][t]),
                             fmaxf(redc[2][t], redc[3][t]));
            nbp[(j0 + t) * 64 + bi] = cv;                  // col-path slot
        }
    }

    // ---- completion: last block touching a panel finishes that panel ----
    __threadfence();   // release: nbp stores visible device-wide before count
    if (t == 0) {
        s_fin[0] = (atomicAdd(&pcnt[bi], 1) == 63) ? bi : -1;
        s_fin[1] = (bi != bj && atomicAdd(&pcnt[bj], 1) == 63) ? bj : -1;
    }
    __syncthreads();
    if (s_fin[0] < 0 && s_fin[1] < 0) return;
    __threadfence();   // acquire: see all other blocks' nbp stores

    #pragma unroll
    for (int fi = 0; fi < 2; ++fi) {
        int p = s_fin[fi];
        if (p < 0) continue;
        float acc2 = 0.f;
        for (int k = 0; k < 16; ++k) {
            int row = p * 128 + w * 16 + k;                // 8 waves x 16 rows
            int c = lab[row];
            ushort2 xb = *reinterpret_cast<const ushort2*>(fb + row * DIM + lane * 2);
            float x0 = __uint_as_float((unsigned)xb.x << 16);
            float x1 = __uint_as_float((unsigned)xb.y << 16);
            float2 y = *reinterpret_cast<const float2*>(cs + c * DIM + lane * 2);
            float s = x0 * y.x + x1 * y.y;
            float nm = ((const volatile float*)nbp)[row * 64 + lane];
            #pragma unroll
            for (int off = 32; off; off >>= 1) {
                s += __shfl_xor(s, off);
                nm = fmaxf(nm, __shfl_xor(nm, off));
            }
            if (lane == 0) {
                float neg = nm > -1e8f ? nm : 0.0f;
                int cnt = hist[c] - 1;
                float pos = cnt > 0 ? (s - 1.0f) / (float)cnt : 0.0f;
                acc2 += fmaxf(0.0f, MARGIN + neg - pos);
            }
        }
        if (lane == 0) sm[w] = acc2;
        __syncthreads();
        if (t == 0) {
            float ps = ((sm[0] + sm[1]) + (sm[2] + sm[3])) +
                       ((sm[4] + sm[5]) + (sm[6] + sm[7]));
            lpart[p] = ps;
            __threadfence();                                // release lpart
            if (atomicAdd(&pcnt[64], 1) == 63) {            // last panel done
                __threadfence();                            // acquire lpart
                float tot = 0.f;
                for (int i = 0; i < 64; ++i)                // fixed order: deterministic
                    tot += ((const volatile float*)lpart)[i];
                out[0] = tot * (1.0f / (float)N_ROWS);
            }
        }
        __syncthreads();
    }
}

extern "C" void kernel_launch(void* const* d_in, const int* in_sizes, int n_in,
                              void* d_out, int out_size, void* d_ws, size_t ws_size,
                              hipStream_t stream) {
    const float* feat = (const float*)d_in[0];
    const int* lab    = (const int*)d_in[1];
    char* ws = (char*)d_ws;
    u16*      fb    = (u16*)ws;                                    // 2 MB
    float*    cs    = (float*)(ws + (2u << 20));                   // 256 KB
    float*    nbp   = (float*)(ws + (2u << 20) + (256u << 10));    // 2 MB [8192][64]
    int*      hist  = (int*)(ws + (4u << 20) + (256u << 10));      // 2 KB
    float*    lpart = (float*)(ws + (4u << 20) + (258u << 10));    // 1 KB
    int*      pcnt  = (int*)(ws + (4u << 20) + (259u << 10));      // 65 ints
    float*    out   = (float*)d_out;

    k_prep2 <<<2560, 256, 0, stream>>>(feat, lab, fb, cs, hist, pcnt);
    k_main  <<<2080, 512, 0, stream>>>(fb, lab, nbp, cs, hist, pcnt, lpart, out);
}

// Round 9
// 55.151 us; speedup vs baseline: 9.3580x; 9.3580x over previous
//
#include <hip/hip_runtime.h>
#include <hip/hip_bf16.h>

#define N_ROWS 8192
#define DIM    128
#define NCLASS 512
#define MARGIN 0.3f

typedef unsigned short u16;
typedef __attribute__((ext_vector_type(8))) short bf16x8;
typedef __attribute__((ext_vector_type(4))) float f32x4;

__device__ inline void load_lds16(const u16* g, u16* l) {
    __builtin_amdgcn_global_load_lds((const __attribute__((address_space(1))) void*)g,
                                     (__attribute__((address_space(3))) void*)l, 16, 0, 0);
}

// ---------------- fused prep: normalize->fb (blocks 0..2047) || class sums (2048..2559) ----------------
__global__ void k_prep2(const float* __restrict__ feat, const int* __restrict__ lab,
                        u16* __restrict__ fb, float* __restrict__ cs, int* __restrict__ hist,
                        unsigned long long* __restrict__ lacc) {
    const int t = threadIdx.x, lane = t & 63, w = t >> 6;
    if (blockIdx.x < 2048) {
        // role A: normalize 4 rows -> bf16 fb
        int row = blockIdx.x * 4 + w;
        float2 v = *reinterpret_cast<const float2*>(feat + row * DIM + lane * 2);
        float ss = v.x * v.x + v.y * v.y;
        #pragma unroll
        for (int off = 32; off; off >>= 1) ss += __shfl_xor(ss, off);
        float r = 1.0f / fmaxf(sqrtf(ss), 1e-12f);
        float x = v.x * r, y = v.y * r;
        __hip_bfloat16 bx = __float2bfloat16(x), by = __float2bfloat16(y);
        u16 ux = *reinterpret_cast<u16*>(&bx), uy = *reinterpret_cast<u16*>(&by);
        ushort2 p; p.x = ux; p.y = uy;
        *reinterpret_cast<ushort2*>(fb + row * DIM + lane * 2) = p;
        return;
    }
    // role B: class sum for c (gathers RAW rows, renormalizes in-register)
    __shared__ int s_cnt;
    __shared__ int s_idx[128];
    __shared__ float2 part[4][64];
    const int c = blockIdx.x - 2048;
    if (blockIdx.x == 2048 && t == 0) lacc[0] = 0ull;   // re-zero accumulator each call
    if (t == 0) s_cnt = 0;
    __syncthreads();
    for (int q = t; q < N_ROWS / 4; q += 256) {
        int4 L = reinterpret_cast<const int4*>(lab)[q];
        if (L.x == c) { int p = atomicAdd(&s_cnt, 1); if (p < 128) s_idx[p] = q * 4 + 0; }
        if (L.y == c) { int p = atomicAdd(&s_cnt, 1); if (p < 128) s_idx[p] = q * 4 + 1; }
        if (L.z == c) { int p = atomicAdd(&s_cnt, 1); if (p < 128) s_idx[p] = q * 4 + 2; }
        if (L.w == c) { int p = atomicAdd(&s_cnt, 1); if (p < 128) s_idx[p] = q * 4 + 3; }
    }
    __syncthreads();
    int cnt = s_cnt < 128 ? s_cnt : 128;
    float sA = 0.f, sB = 0.f;          // lane owns dims 2*lane, 2*lane+1
    for (int p = w; p < cnt; p += 4) { // waves split the class rows
        int r = s_idx[p];
        float2 v = *reinterpret_cast<const float2*>(feat + r * DIM + lane * 2);
        float ss = v.x * v.x + v.y * v.y;
        #pragma unroll
        for (int off = 32; off; off >>= 1) ss += __shfl_xor(ss, off);
        float rr = 1.0f / fmaxf(sqrtf(ss), 1e-12f);
        sA += v.x * rr; sB += v.y * rr;
    }
    part[w][lane] = make_float2(sA, sB);
    __syncthreads();
    if (t < 64) {
        float2 p0 = part[0][t], p1 = part[1][t], p2 = part[2][t], p3 = part[3][t];
        float2 o = make_float2((p0.x + p1.x) + (p2.x + p3.x),
                               (p0.y + p1.y) + (p2.y + p3.y));
        *reinterpret_cast<float2*>(cs + c * DIM + t * 2) = o;
    }
    if (t == 0) hist[c] = s_cnt;
}

// ---------------- main: symmetric fused sim-GEMM + masked neg-max ----------------
// Upper-triangle tiles only: 2080 blocks, each computes one 128x128 tile (bi<=bj)
// and emits BOTH row-direction (panel bi) and col-direction (panel bj) masked
// maxes (sim and the label mask are symmetric). 512 thr = 8 waves (4 wr x 2 wc),
// wave tile 32x64. B staged once via global_load_lds (source-XOR-swizzle, linear
// LDS dest). nbp[row][64]: slot bj from row path, slot bi from col path; diagonal
// block writes row path only => every slot written exactly once, no atomics.
// NOTE (r8 post-mortem): NO device fences / cross-block reads in here — plain
// stores + kernel boundary is the only fast coherence path on multi-XCD CDNA4.
__global__ __launch_bounds__(512, 4) void k_main(const u16* __restrict__ fb,
                                                 const int* __restrict__ lab,
                                                 float* __restrict__ nbp) {
    __shared__ u16 Bt[128 * 128];         // 32 KB
    __shared__ float redr[2][128];        // row partials by wc
    __shared__ float redc[4][128];        // col partials by wr
    const int t = threadIdx.x;
    const int lane = t & 63, w = t >> 6;
    const int wr = w >> 1, wc = w & 1;    // wr 0..3 (32-row strips), wc 0..1 (64-col strips)
    const int l15 = lane & 15, l4 = lane >> 4;

    // invert linear block id -> (bi, bj) upper triangle, bi<=bj, 64x64 panels
    int tt = blockIdx.x;
    int bi = (int)((129.0f - sqrtf(16641.0f - 8.0f * (float)tt)) * 0.5f);
    while (bi * 64 - bi * (bi - 1) / 2 > tt) --bi;
    while ((bi + 1) * 64 - (bi + 1) * bi / 2 <= tt) ++bi;
    const int bj = bi + (tt - (bi * 64 - bi * (bi - 1) / 2));
    const int i0 = bi * 128, j0 = bj * 128;

    // stage B tile = fb rows j0..j0+127 (2048 x 16B chunks, 4 per thread)
    #pragma unroll
    for (int it = 0; it < 4; ++it) {
        int q = it * 512 + t;
        int brow = q >> 4, kb = q & 15;
        load_lds16(fb + (j0 + brow) * DIM + ((kb ^ (brow & 7)) * 8), Bt + q * 8);
    }

    // A fragments: row = i0 + wr*32 + m*16 + l15, k = ks*32 + l4*8
    bf16x8 a[2][4];
    #pragma unroll
    for (int m = 0; m < 2; ++m)
        #pragma unroll
        for (int ks = 0; ks < 4; ++ks)
            a[m][ks] = *reinterpret_cast<const bf16x8*>(
                fb + (i0 + wr * 32 + m * 16 + l15) * DIM + ks * 32 + l4 * 8);

    // output-row labels: row = i0 + wr*32 + m*16 + l4*4 + rg
    int labr[2][4];
    #pragma unroll
    for (int m = 0; m < 2; ++m)
        #pragma unroll
        for (int rg = 0; rg < 4; ++rg)
            labr[m][rg] = lab[i0 + wr * 32 + m * 16 + l4 * 4 + rg];

    // column labels: col = j0 + wc*64 + n*16 + l15
    int labc[4];
    #pragma unroll
    for (int n = 0; n < 4; ++n) labc[n] = lab[j0 + wc * 64 + n * 16 + l15];

    __syncthreads();   // compiler drains vmcnt before barrier -> Bt ready

    f32x4 acc[2][4];
    #pragma unroll
    for (int m = 0; m < 2; ++m)
        #pragma unroll
        for (int n = 0; n < 4; ++n) acc[m][n] = f32x4{0.f, 0.f, 0.f, 0.f};

    __builtin_amdgcn_s_setprio(1);
    #pragma unroll
    for (int ks = 0; ks < 4; ++ks) {
        bf16x8 b[4];
        #pragma unroll
        for (int n = 0; n < 4; ++n) {
            int brow = wc * 64 + n * 16 + l15;
            int kb = ks * 4 + l4;
            b[n] = *reinterpret_cast<const bf16x8*>(
                Bt + brow * DIM + ((kb ^ (brow & 7)) * 8));
        }
        #pragma unroll
        for (int m = 0; m < 2; ++m)
            #pragma unroll
            for (int n = 0; n < 4; ++n)
                acc[m][n] = __builtin_amdgcn_mfma_f32_16x16x32_bf16(a[m][ks], b[n],
                                                                    acc[m][n], 0, 0, 0);
    }
    __builtin_amdgcn_s_setprio(0);

    // masked epilogue: v computed once, feeds row-max AND col-max
    float negp[2][4];
    float colv[4];
    #pragma unroll
    for (int m = 0; m < 2; ++m)
        #pragma unroll
        for (int rg = 0; rg < 4; ++rg) negp[m][rg] = -1e9f;
    #pragma unroll
    for (int n = 0; n < 4; ++n) colv[n] = -1e9f;

    #pragma unroll
    for (int m = 0; m < 2; ++m)
        #pragma unroll
        for (int n = 0; n < 4; ++n) {
            int lc = labc[n];
            #pragma unroll
            for (int rg = 0; rg < 4; ++rg) {
                float s = acc[m][n][rg];
                float v = (labr[m][rg] != lc) ? s : -1e9f;
                negp[m][rg] = fmaxf(negp[m][rg], v);
                colv[n] = fmaxf(colv[n], v);
            }
        }

    // row reduce across the 16 lanes (cols) sharing each row
    #pragma unroll
    for (int m = 0; m < 2; ++m)
        #pragma unroll
        for (int rg = 0; rg < 4; ++rg) {
            float v = negp[m][rg];
            v = fmaxf(v, __shfl_xor(v, 1));
            v = fmaxf(v, __shfl_xor(v, 2));
            v = fmaxf(v, __shfl_xor(v, 4));
            v = fmaxf(v, __shfl_xor(v, 8));
            negp[m][rg] = v;
        }
    if (l15 == 0) {
        #pragma unroll
        for (int m = 0; m < 2; ++m)
            #pragma unroll
            for (int rg = 0; rg < 4; ++rg)
                redr[wc][wr * 32 + m * 16 + l4 * 4 + rg] = negp[m][rg];
    }

    // col reduce across the 4 l4 groups (rows) sharing each col
    #pragma unroll
    for (int n = 0; n < 4; ++n) {
        float v = colv[n];
        v = fmaxf(v, __shfl_xor(v, 16));
        v = fmaxf(v, __shfl_xor(v, 32));
        colv[n] = v;
    }
    if (l4 == 0) {
        #pragma unroll
        for (int n = 0; n < 4; ++n)
            redc[wr][wc * 64 + n * 16 + l15] = colv[n];
    }
    __syncthreads();

    if (t < 128) {
        float rv = fmaxf(redr[0][t], redr[1][t]);
        nbp[(i0 + t) * 64 + bj] = rv;                      // row-path slot, exactly once
        if (bi != bj) {
            float cv = fmaxf(fmaxf(redc[0][t], redc[1][t]),
                             fmaxf(redc[2][t], redc[3][t]));
            nbp[(j0 + t) * 64 + bi] = cv;                  // col-path slot, exactly once
        }
    }
}

// ---------------- fused posdot + neg-reduce + loss + final (single-atomic finish) ----------------
// 256 blocks x 4 waves, one row per wave-iteration: lane = nbp slot (64 slots),
// bf16 per-lane dot, single shfl chain sum+max. Block partial quantized to
// fixed-point (x2^24; integer add = associative = deterministic) and merged with
// a SINGLE u64 atomicAdd carrying {count<<48 | sum} — the block that sees
// count==256 in the returned value already holds the full sum. No fences.
__global__ void k_loss(const u16* __restrict__ fb, const float* __restrict__ cs,
                       const int* __restrict__ lab, const float* __restrict__ nbp,
                       const int* __restrict__ hist,
                       unsigned long long* __restrict__ lacc, float* __restrict__ out) {
    int t = threadIdx.x, lane = t & 63, w = t >> 6;
    int rbase = blockIdx.x * 32 + w * 8;
    float acc = 0.f;
    #pragma unroll
    for (int k = 0; k < 8; ++k) {
        int row = rbase + k;
        int c = lab[row];
        ushort2 xb = *reinterpret_cast<const ushort2*>(fb + row * DIM + lane * 2);
        float x0 = __uint_as_float((unsigned)xb.x << 16);
        float x1 = __uint_as_float((unsigned)xb.y << 16);
        float2 y = *reinterpret_cast<const float2*>(cs + c * DIM + lane * 2);
        float s = x0 * y.x + x1 * y.y;
        float nm = nbp[row * 64 + lane];
        #pragma unroll
        for (int off = 32; off; off >>= 1) {
            s += __shfl_xor(s, off);
            nm = fmaxf(nm, __shfl_xor(nm, off));
        }
        if (lane == 0) {
            float neg = nm > -1e8f ? nm : 0.0f;
            int cnt = hist[c] - 1;
            float pos = cnt > 0 ? (s - 1.0f) / (float)cnt : 0.0f;
            acc += fmaxf(0.0f, MARGIN + neg - pos);
        }
    }
    __shared__ float sm[4];
    if (lane == 0) sm[w] = acc;
    __syncthreads();
    if (t == 0) {
        float ps = (sm[0] + sm[1]) + (sm[2] + sm[3]);
        unsigned long long q = (unsigned long long)llrintf(ps * 16777216.0f); // ps*2^24, < 2^31
        unsigned long long add = q + (1ull << 48);
        unsigned long long newv = atomicAdd(lacc, add) + add;
        if ((newv >> 48) == 256ull) {        // last block: low 48 bits = full sum
            double tot = (double)(newv & 0xFFFFFFFFFFFFull);
            out[0] = (float)(tot * (1.0 / (16777216.0 * 8192.0)));
        }
    }
}

extern "C" void kernel_launch(void* const* d_in, const int* in_sizes, int n_in,
                              void* d_out, int out_size, void* d_ws, size_t ws_size,
                              hipStream_t stream) {
    const float* feat = (const float*)d_in[0];
    const int* lab    = (const int*)d_in[1];
    char* ws = (char*)d_ws;
    u16*      fb    = (u16*)ws;                                    // 2 MB
    float*    cs    = (float*)(ws + (2u << 20));                   // 256 KB
    float*    nbp   = (float*)(ws + (2u << 20) + (256u << 10));    // 2 MB [8192][64]
    int*      hist  = (int*)(ws + (4u << 20) + (256u << 10));      // 2 KB
    unsigned long long* lacc = (unsigned long long*)(ws + (4u << 20) + (258u << 10));
    float*    out   = (float*)d_out;

    k_prep2 <<<2560, 256, 0, stream>>>(feat, lab, fb, cs, hist, lacc);
    k_main  <<<2080, 512, 0, stream>>>(fb, lab, nbp);
    k_loss  <<<256,  256, 0, stream>>>(fb, cs, lab, nbp, hist, lacc, out);
}